// Round 6
// baseline (680.499 us; speedup 1.0000x reference)
//
#include <hip/hip_runtime.h>
#include <math.h>

#define N_USERS 100000
#define N_ITEMS 40000
#define N_NODES (N_USERS + N_ITEMS)
#define EMB 128
#define EMBW (EMB / 2)            /* 64 uints of packed 2xbf16 per row */
#define BATCH 8192
#define N_EDGES 1000000
#define NNZ (2 * N_EDGES)
#define N_LAYERS 3
#define ALPHA 0.1f
#define GAMMA 0.01f

#define SCAN_BLOCKS 256
#define SCAN_CHUNK ((N_NODES + SCAN_BLOCKS - 1) / SCAN_BLOCKS)   /* 547 */
#define SCAN_PER_THREAD ((SCAN_CHUNK + 255) / 256)               /* 3 */

// ---------- bf16 pack/unpack (RNE) -------------------------------------------
__device__ inline unsigned int f2bf(float x) {
    const unsigned int b = __float_as_uint(x);
    return (b + 0x7FFFu + ((b >> 16) & 1u)) >> 16;
}
__device__ inline float bfl(unsigned int w) { return __uint_as_float(w << 16); }
__device__ inline float bfh(unsigned int w) { return __uint_as_float(w & 0xFFFF0000u); }

// ---------------- CSR build step 1: degree histogram --------------------------
__global__ void hist_kernel(const int* __restrict__ edge_user,
                            const int* __restrict__ edge_item,
                            int* __restrict__ deg) {
    int i = blockIdx.x * blockDim.x + threadIdx.x;
    const int stride = gridDim.x * blockDim.x;
    for (; i < NNZ; i += stride) {
        const int row = (i < N_EDGES) ? edge_user[i]
                                      : N_USERS + edge_item[i - N_EDGES];
        atomicAdd(&deg[row], 1);
    }
}

// ---------------- CSR scan phase 1: per-block chunk sums ----------------------
__global__ void partial_kernel(const int* __restrict__ deg, int* __restrict__ bsum) {
    const int b = blockIdx.x;
    const int t = threadIdx.x;
    const int base = b * SCAN_CHUNK + t * SCAN_PER_THREAD;
    const int lim = min((b + 1) * SCAN_CHUNK, N_NODES);
    int s = 0;
    #pragma unroll
    for (int k = 0; k < SCAN_PER_THREAD; ++k) {
        const int i = base + k;
        if (i < lim) s += deg[i];
    }
    __shared__ int red[4];
    #pragma unroll
    for (int off = 32; off > 0; off >>= 1) s += __shfl_down(s, off);
    const int lane = t & 63, wid = t >> 6;
    if (lane == 0) red[wid] = s;
    __syncthreads();
    if (t == 0) bsum[b] = red[0] + red[1] + red[2] + red[3];
}

// ---------------- CSR scan phase 2: scan 256 block sums -----------------------
__global__ void scanb_kernel(const int* __restrict__ bsum, int* __restrict__ boff,
                             int* __restrict__ row_start) {
    const int t = threadIdx.x;        // 256 threads
    const int lane = t & 63, wid = t >> 6;
    const int v = bsum[t];
    int x = v;
    #pragma unroll
    for (int off = 1; off < 64; off <<= 1) {
        const int y = __shfl_up(x, off);
        if (lane >= off) x += y;
    }
    __shared__ int wtot[4];
    if (lane == 63) wtot[wid] = x;
    __syncthreads();
    int wo = 0;
    for (int k = 0; k < wid; ++k) wo += wtot[k];
    boff[t] = wo + x - v;
    if (t == 255) row_start[N_NODES] = wo + x;   // == NNZ
}

// ---------------- CSR scan phase 3: emit row_start/row_cur + inv_sqrt ---------
__global__ void emit_kernel(const int* __restrict__ deg, const int* __restrict__ boff,
                            int* __restrict__ row_start, int* __restrict__ row_cur,
                            float* __restrict__ inv_sqrt) {
    const int b = blockIdx.x;
    const int t = threadIdx.x;
    const int lane = t & 63, wid = t >> 6;
    const int base = b * SCAN_CHUNK + t * SCAN_PER_THREAD;
    const int lim = min((b + 1) * SCAN_CHUNK, N_NODES);
    int d[SCAN_PER_THREAD];
    int s = 0;
    #pragma unroll
    for (int k = 0; k < SCAN_PER_THREAD; ++k) {
        const int i = base + k;
        d[k] = (i < lim) ? deg[i] : 0;
        s += d[k];
    }
    int x = s;
    #pragma unroll
    for (int off = 1; off < 64; off <<= 1) {
        const int y = __shfl_up(x, off);
        if (lane >= off) x += y;
    }
    __shared__ int wtot[4];
    if (lane == 63) wtot[wid] = x;
    __syncthreads();
    int wo = boff[b];
    for (int k = 0; k < wid; ++k) wo += wtot[k];
    int p = wo + x - s;
    #pragma unroll
    for (int k = 0; k < SCAN_PER_THREAD; ++k) {
        const int i = base + k;
        if (i < lim) {
            row_start[i] = p;
            row_cur[i]   = p;
            inv_sqrt[i]  = (d[k] > 0) ? (1.0f / sqrtf((float)d[k])) : 0.0f;
            p += d[k];
        }
    }
}

// ---------------- CSR build: scatter edge cols (no vals!) ---------------------
__global__ void scatter_kernel(const int* __restrict__ edge_user,
                               const int* __restrict__ edge_item,
                               int* __restrict__ row_cur,
                               int* __restrict__ csr_col) {
    int i = blockIdx.x * blockDim.x + threadIdx.x;
    const int stride = gridDim.x * blockDim.x;
    for (; i < NNZ; i += stride) {
        int row, col;
        if (i < N_EDGES) { row = edge_user[i];            col = N_USERS + edge_item[i]; }
        else { const int e = i - N_EDGES; row = N_USERS + edge_item[e]; col = edge_user[e]; }
        const int pos = atomicAdd(&row_cur[row], 1);
        csr_col[pos] = col;
    }
}

// ---------------- init: e0 = bf16(inv_sqrt[node] * x0) ------------------------
__global__ void init_kernel(const float* __restrict__ user_emb,
                            const float* __restrict__ item_emb,
                            const float* __restrict__ inv_sqrt,
                            unsigned int* __restrict__ e0) {
    const int total = N_NODES * EMBW;
    const int u64c  = N_USERS * EMBW;
    int i = blockIdx.x * blockDim.x + threadIdx.x;
    const int stride = gridDim.x * blockDim.x;
    for (; i < total; i += stride) {
        float2 v;
        if (i < u64c) v = ((const float2*)user_emb)[i];
        else          v = ((const float2*)item_emb)[i - u64c];
        const float n = inv_sqrt[i >> 6];
        e0[i] = f2bf(n * v.x) | (f2bf(n * v.y) << 16);
    }
}

// ---------------- SpMM (scaled propagation): w'[r] = n[r]^2 * sum w[c] --------
// one 64-lane wave per row; one packed uint (2 bf16) per lane covers EMB=128.
__global__ void spmm_bf16_kernel(const unsigned int* __restrict__ cur,
                                 unsigned int* __restrict__ nxt,
                                 const int* __restrict__ row_start,
                                 const int* __restrict__ csr_col,
                                 const float* __restrict__ inv_sqrt) {
    const int lane = threadIdx.x & 63;
    const int w = blockIdx.x * (blockDim.x >> 6) + (threadIdx.x >> 6);
    if (w >= N_NODES) return;
    const int beg = row_start[w];
    const int end = row_start[w + 1];
    float sx = 0.f, sy = 0.f;
    int j = beg;
    for (; j + 1 < end; j += 2) {
        const int c0 = csr_col[j];
        const int c1 = csr_col[j + 1];
        const unsigned int w0 = cur[(size_t)c0 * EMBW + lane];
        const unsigned int w1 = cur[(size_t)c1 * EMBW + lane];
        sx += bfl(w0) + bfl(w1);
        sy += bfh(w0) + bfh(w1);
    }
    if (j < end) {
        const int c0 = csr_col[j];
        const unsigned int w0 = cur[(size_t)c0 * EMBW + lane];
        sx += bfl(w0);
        sy += bfh(w0);
    }
    const float n = inv_sqrt[w];
    const float scale = n * n;
    nxt[(size_t)w * EMBW + lane] = f2bf(scale * sx) | (f2bf(scale * sy) << 16);
}

__device__ inline float logsigmoidf(float x) {
    return (x >= 0.f) ? -log1pf(expf(-x)) : (x - log1pf(expf(x)));
}

// ---------------- fused losses ------------------------------------------------
// acc-row on the fly: x0(fp32) + sqrt(deg)*(w1+w2+w3), dot, /16.
__global__ void loss_kernel(const float* __restrict__ user_emb,
                            const float* __restrict__ item_emb,
                            const unsigned int* __restrict__ e1,
                            const unsigned int* __restrict__ e2,
                            const unsigned int* __restrict__ e3,
                            const int* __restrict__ deg,
                            const int* __restrict__ users,
                            const int* __restrict__ pos_items,
                            const int* __restrict__ neg_items,
                            const int* __restrict__ sampled_user,
                            const int* __restrict__ sampled_items,
                            float* __restrict__ sums) {
    const int lane = threadIdx.x & 63;
    const int wid  = threadIdx.x >> 6;            // 0..3
    const int gw   = blockIdx.x * 4 + wid;
    const int nw   = gridDim.x * 4;
    float s_bce = 0.f, s_pred = 0.f, s_plogp = 0.f, s_ul = 0.f;
    for (int p = gw; p < 4 * BATCH; p += nw) {
        int u, it;
        if (p < 2 * BATCH) {
            if (p < BATCH) { u = users[p];          it = pos_items[p]; }
            else           { u = users[p - BATCH];  it = neg_items[p - BATCH]; }
        } else {
            const int q = p - 2 * BATCH;
            u = sampled_user[q]; it = sampled_items[q];
        }
        const float sdu = sqrtf((float)deg[u]);
        const float2 a0 = ((const float2*)(user_emb + (size_t)u * EMB))[lane];
        const size_t ui = (size_t)u * EMBW + lane;
        const unsigned int u1 = e1[ui], u2 = e2[ui], u3 = e3[ui];
        const float ax = a0.x + sdu * (bfl(u1) + bfl(u2) + bfl(u3));
        const float ay = a0.y + sdu * (bfh(u1) + bfh(u2) + bfh(u3));
        const int itn = N_USERS + it;
        const float sdi = sqrtf((float)deg[itn]);
        const float2 b0 = ((const float2*)(item_emb + (size_t)it * EMB))[lane];
        const size_t ii = (size_t)itn * EMBW + lane;
        const unsigned int i1 = e1[ii], i2 = e2[ii], i3 = e3[ii];
        const float bx = b0.x + sdi * (bfl(i1) + bfl(i2) + bfl(i3));
        const float by = b0.y + sdi * (bfh(i1) + bfh(i2) + bfh(i3));
        float d = ax * bx + ay * by;
        #pragma unroll
        for (int off = 32; off > 0; off >>= 1) d += __shfl_down(d, off);
        if (lane == 0) {
            d *= (1.f / 16.f);                  // (acc/4)·(acc/4)
            const float pred = 1.f / (1.f + expf(-d));
            if (p < 2 * BATCH) {
                const float ls  = logsigmoidf(d);
                const float lsn = logsigmoidf(-d);
                s_bce   += (p < BATCH) ? -ls : -lsn;
                s_pred  += pred;
                s_plogp += pred * ls;
            } else {
                s_ul += pred;
            }
        }
    }
    __shared__ float red[4][4];
    if (lane == 0) {
        red[wid][0] = s_bce; red[wid][1] = s_pred;
        red[wid][2] = s_plogp; red[wid][3] = s_ul;
    }
    __syncthreads();
    if (threadIdx.x < 4) {
        const float v = red[0][threadIdx.x] + red[1][threadIdx.x]
                      + red[2][threadIdx.x] + red[3][threadIdx.x];
        atomicAdd(&sums[threadIdx.x], v);
    }
}

// ---------------- finalize ----------------------------------------------------
__global__ void finalize_kernel(const float* __restrict__ sums, float* __restrict__ out) {
    if (threadIdx.x == 0 && blockIdx.x == 0) {
        const float n = 2.f * BATCH;
        const float bce        = sums[0] / n;
        const float pred_avg   = sums[1] / n;
        const float plogp_avg  = sums[2] / n;
        const float predul_avg = sums[3] / n;
        const float info = ALPHA * (-pred_avg * logf(predul_avg)
                                    - (1.f - pred_avg) * logf(1.f - predul_avg))
                         + GAMMA * plogp_avg;
        out[0] = bce;
        out[1] = info;
    }
}

extern "C" void kernel_launch(void* const* d_in, const int* in_sizes, int n_in,
                              void* d_out, int out_size, void* d_ws, size_t ws_size,
                              hipStream_t stream) {
    const float* user_emb      = (const float*)d_in[0];
    const float* item_emb      = (const float*)d_in[1];
    const int*   edge_user     = (const int*)d_in[3];
    const int*   edge_item     = (const int*)d_in[4];
    const int*   users         = (const int*)d_in[5];
    const int*   pos_items     = (const int*)d_in[6];
    const int*   neg_items     = (const int*)d_in[7];
    const int*   sampled_user  = (const int*)d_in[8];
    const int*   sampled_items = (const int*)d_in[9];
    float* out = (float*)d_out;

    const size_t ebytes = (size_t)N_NODES * EMBW * sizeof(unsigned int); // 35.84 MB
    char* ws = (char*)d_ws;
    size_t off = 0;
    unsigned int* e0 = (unsigned int*)(ws + off); off += ebytes;
    unsigned int* e1 = (unsigned int*)(ws + off); off += ebytes;
    unsigned int* e2 = (unsigned int*)(ws + off); off += ebytes;
    unsigned int* e3 = (unsigned int*)(ws + off); off += ebytes;
    float* sums = (float*)(ws + off); off += 256;
    int*   deg       = (int*)(ws + off); off += (size_t)N_NODES * 4;
    int*   row_start = (int*)(ws + off); off += (size_t)(N_NODES + 1) * 4 + 252;
    int*   row_cur   = (int*)(ws + off); off += (size_t)N_NODES * 4;
    float* inv_sqrt  = (float*)(ws + off); off += (size_t)N_NODES * 4;
    int*   csr_col   = (int*)(ws + off); off += (size_t)NNZ * 4;
    int*   bsum      = (int*)(ws + off); off += (size_t)SCAN_BLOCKS * 4;
    int*   boff      = (int*)(ws + off); off += (size_t)SCAN_BLOCKS * 4;

    hipMemsetAsync(deg, 0, (size_t)N_NODES * 4, stream);
    hipMemsetAsync(sums, 0, 4 * sizeof(float), stream);

    hist_kernel<<<2048, 256, 0, stream>>>(edge_user, edge_item, deg);
    partial_kernel<<<SCAN_BLOCKS, 256, 0, stream>>>(deg, bsum);
    scanb_kernel<<<1, 256, 0, stream>>>(bsum, boff, row_start);
    emit_kernel<<<SCAN_BLOCKS, 256, 0, stream>>>(deg, boff, row_start, row_cur,
                                                 inv_sqrt);
    scatter_kernel<<<2048, 256, 0, stream>>>(edge_user, edge_item, row_cur, csr_col);
    init_kernel<<<4096, 256, 0, stream>>>(user_emb, item_emb, inv_sqrt, e0);

    spmm_bf16_kernel<<<(N_NODES + 3) / 4, 256, 0, stream>>>(e0, e1, row_start,
                                                            csr_col, inv_sqrt);
    spmm_bf16_kernel<<<(N_NODES + 3) / 4, 256, 0, stream>>>(e1, e2, row_start,
                                                            csr_col, inv_sqrt);
    spmm_bf16_kernel<<<(N_NODES + 3) / 4, 256, 0, stream>>>(e2, e3, row_start,
                                                            csr_col, inv_sqrt);

    loss_kernel<<<512, 256, 0, stream>>>(user_emb, item_emb, e1, e2, e3, deg,
                                         users, pos_items, neg_items,
                                         sampled_user, sampled_items, sums);
    finalize_kernel<<<1, 1, 0, stream>>>(sums, out);
}

// Round 7
// 621.359 us; speedup vs baseline: 1.0952x; 1.0952x over previous
//
#include <hip/hip_runtime.h>
#include <math.h>

#define N_USERS 100000
#define N_ITEMS 40000
#define N_NODES (N_USERS + N_ITEMS)
#define EMB 128
#define EMBW (EMB / 2)            /* 64 uints of packed 2xbf16 per row */
#define BATCH 8192
#define N_EDGES 1000000
#define NNZ (2 * N_EDGES)
#define N_LAYERS 3
#define ALPHA 0.1f
#define GAMMA 0.01f
#define NGRP 8                    /* one group per XCD (blockIdx % 8 heuristic) */

#define SCAN_BLOCKS 256
#define SCAN_CHUNK ((N_NODES + SCAN_BLOCKS - 1) / SCAN_BLOCKS)   /* 547 */
#define SCAN_PER_THREAD ((SCAN_CHUNK + 255) / 256)               /* 3 */

// ---------- bf16 pack/unpack (RNE) -------------------------------------------
__device__ inline unsigned int f2bf(float x) {
    const unsigned int b = __float_as_uint(x);
    return (b + 0x7FFFu + ((b >> 16) & 1u)) >> 16;
}
__device__ inline float bfl(unsigned int w) { return __uint_as_float(w << 16); }
__device__ inline float bfh(unsigned int w) { return __uint_as_float(w & 0xFFFF0000u); }

// ---------------- CSR build step 1: degree histogram (XCD-grouped) ------------
// block b handles only rows in static range-group (b & 7); with blockIdx%8->XCD
// round-robin, each deg line is RMW'd by a single XCD's L2.
__global__ void hist_kernel(const int* __restrict__ edge_user,
                            const int* __restrict__ edge_item,
                            int* __restrict__ deg) {
    const int g = blockIdx.x & (NGRP - 1);
    int i = (blockIdx.x >> 3) * blockDim.x + threadIdx.x;
    const int stride = (gridDim.x >> 3) * blockDim.x;
    for (; i < NNZ; i += stride) {
        const int row = (i < N_EDGES) ? edge_user[i]
                                      : N_USERS + edge_item[i - N_EDGES];
        const int rg = (row * NGRP) / N_NODES;
        if (rg == g) atomicAdd(&deg[row], 1);
    }
}

// ---------------- CSR scan phase 1: per-block chunk sums ----------------------
__global__ void partial_kernel(const int* __restrict__ deg, int* __restrict__ bsum) {
    const int b = blockIdx.x;
    const int t = threadIdx.x;
    const int base = b * SCAN_CHUNK + t * SCAN_PER_THREAD;
    const int lim = min((b + 1) * SCAN_CHUNK, N_NODES);
    int s = 0;
    #pragma unroll
    for (int k = 0; k < SCAN_PER_THREAD; ++k) {
        const int i = base + k;
        if (i < lim) s += deg[i];
    }
    __shared__ int red[4];
    #pragma unroll
    for (int off = 32; off > 0; off >>= 1) s += __shfl_down(s, off);
    const int lane = t & 63, wid = t >> 6;
    if (lane == 0) red[wid] = s;
    __syncthreads();
    if (t == 0) bsum[b] = red[0] + red[1] + red[2] + red[3];
}

// ---------------- CSR scan phase 2: scan 256 block sums -----------------------
__global__ void scanb_kernel(const int* __restrict__ bsum, int* __restrict__ boff,
                             int* __restrict__ row_start) {
    const int t = threadIdx.x;        // 256 threads
    const int lane = t & 63, wid = t >> 6;
    const int v = bsum[t];
    int x = v;
    #pragma unroll
    for (int off = 1; off < 64; off <<= 1) {
        const int y = __shfl_up(x, off);
        if (lane >= off) x += y;
    }
    __shared__ int wtot[4];
    if (lane == 63) wtot[wid] = x;
    __syncthreads();
    int wo = 0;
    for (int k = 0; k < wid; ++k) wo += wtot[k];
    boff[t] = wo + x - v;
    if (t == 255) row_start[N_NODES] = wo + x;   // == NNZ
}

// -------- CSR scan phase 3: emit row_start/row_cur + inv_sqrt + row_grp -------
__global__ void emit_kernel(const int* __restrict__ deg, const int* __restrict__ boff,
                            int* __restrict__ row_start, int* __restrict__ row_cur,
                            float* __restrict__ inv_sqrt,
                            unsigned char* __restrict__ row_grp) {
    const int b = blockIdx.x;
    const int t = threadIdx.x;
    const int lane = t & 63, wid = t >> 6;
    const int base = b * SCAN_CHUNK + t * SCAN_PER_THREAD;
    const int lim = min((b + 1) * SCAN_CHUNK, N_NODES);
    int d[SCAN_PER_THREAD];
    int s = 0;
    #pragma unroll
    for (int k = 0; k < SCAN_PER_THREAD; ++k) {
        const int i = base + k;
        d[k] = (i < lim) ? deg[i] : 0;
        s += d[k];
    }
    int x = s;
    #pragma unroll
    for (int off = 1; off < 64; off <<= 1) {
        const int y = __shfl_up(x, off);
        if (lane >= off) x += y;
    }
    __shared__ int wtot[4];
    if (lane == 63) wtot[wid] = x;
    __syncthreads();
    int wo = boff[b];
    for (int k = 0; k < wid; ++k) wo += wtot[k];
    int p = wo + x - s;
    #pragma unroll
    for (int k = 0; k < SCAN_PER_THREAD; ++k) {
        const int i = base + k;
        if (i < lim) {
            row_start[i] = p;
            row_cur[i]   = p;
            inv_sqrt[i]  = (d[k] > 0) ? (1.0f / sqrtf((float)d[k])) : 0.0f;
            // equal-nnz group id; empty tail rows may get NGRP (never matched, deg=0)
            row_grp[i]   = (unsigned char)(((long long)p * NGRP) / NNZ);
            p += d[k];
        }
    }
}

// ---------------- CSR build: scatter edge cols (XCD-grouped) ------------------
// block b writes only rows of nnz-balanced group (b & 7): csr_col slice ~1 MB
// stays in one XCD's L2 so lines merge before writeback.
__global__ void scatter_kernel(const int* __restrict__ edge_user,
                               const int* __restrict__ edge_item,
                               const unsigned char* __restrict__ row_grp,
                               int* __restrict__ row_cur,
                               int* __restrict__ csr_col) {
    const int g = blockIdx.x & (NGRP - 1);
    int i = (blockIdx.x >> 3) * blockDim.x + threadIdx.x;
    const int stride = (gridDim.x >> 3) * blockDim.x;
    for (; i < NNZ; i += stride) {
        int row, col;
        if (i < N_EDGES) { row = edge_user[i];            col = N_USERS + edge_item[i]; }
        else { const int e = i - N_EDGES; row = N_USERS + edge_item[e]; col = edge_user[e]; }
        if (row_grp[row] != g) continue;
        const int pos = atomicAdd(&row_cur[row], 1);
        csr_col[pos] = col;
    }
}

// ---------------- init: e0 = bf16(inv_sqrt[node] * x0) ------------------------
__global__ void init_kernel(const float* __restrict__ user_emb,
                            const float* __restrict__ item_emb,
                            const float* __restrict__ inv_sqrt,
                            unsigned int* __restrict__ e0) {
    const int total = N_NODES * EMBW;
    const int u64c  = N_USERS * EMBW;
    int i = blockIdx.x * blockDim.x + threadIdx.x;
    const int stride = gridDim.x * blockDim.x;
    for (; i < total; i += stride) {
        float2 v;
        if (i < u64c) v = ((const float2*)user_emb)[i];
        else          v = ((const float2*)item_emb)[i - u64c];
        const float n = inv_sqrt[i >> 6];
        e0[i] = f2bf(n * v.x) | (f2bf(n * v.y) << 16);
    }
}

// ---------------- SpMM (scaled propagation): w'[r] = n[r]^2 * sum w[c] --------
__global__ void spmm_bf16_kernel(const unsigned int* __restrict__ cur,
                                 unsigned int* __restrict__ nxt,
                                 const int* __restrict__ row_start,
                                 const int* __restrict__ csr_col,
                                 const float* __restrict__ inv_sqrt) {
    const int lane = threadIdx.x & 63;
    const int w = blockIdx.x * (blockDim.x >> 6) + (threadIdx.x >> 6);
    if (w >= N_NODES) return;
    const int beg = row_start[w];
    const int end = row_start[w + 1];
    float sx = 0.f, sy = 0.f;
    int j = beg;
    for (; j + 1 < end; j += 2) {
        const int c0 = csr_col[j];
        const int c1 = csr_col[j + 1];
        const unsigned int w0 = cur[(size_t)c0 * EMBW + lane];
        const unsigned int w1 = cur[(size_t)c1 * EMBW + lane];
        sx += bfl(w0) + bfl(w1);
        sy += bfh(w0) + bfh(w1);
    }
    if (j < end) {
        const int c0 = csr_col[j];
        const unsigned int w0 = cur[(size_t)c0 * EMBW + lane];
        sx += bfl(w0);
        sy += bfh(w0);
    }
    const float n = inv_sqrt[w];
    const float scale = n * n;
    nxt[(size_t)w * EMBW + lane] = f2bf(scale * sx) | (f2bf(scale * sy) << 16);
}

__device__ inline float logsigmoidf(float x) {
    return (x >= 0.f) ? -log1pf(expf(-x)) : (x - log1pf(expf(x)));
}

// ---------------- fused losses ------------------------------------------------
__global__ void loss_kernel(const float* __restrict__ user_emb,
                            const float* __restrict__ item_emb,
                            const unsigned int* __restrict__ e1,
                            const unsigned int* __restrict__ e2,
                            const unsigned int* __restrict__ e3,
                            const int* __restrict__ deg,
                            const int* __restrict__ users,
                            const int* __restrict__ pos_items,
                            const int* __restrict__ neg_items,
                            const int* __restrict__ sampled_user,
                            const int* __restrict__ sampled_items,
                            float* __restrict__ sums) {
    const int lane = threadIdx.x & 63;
    const int wid  = threadIdx.x >> 6;            // 0..3
    const int gw   = blockIdx.x * 4 + wid;
    const int nw   = gridDim.x * 4;
    float s_bce = 0.f, s_pred = 0.f, s_plogp = 0.f, s_ul = 0.f;
    for (int p = gw; p < 4 * BATCH; p += nw) {
        int u, it;
        if (p < 2 * BATCH) {
            if (p < BATCH) { u = users[p];          it = pos_items[p]; }
            else           { u = users[p - BATCH];  it = neg_items[p - BATCH]; }
        } else {
            const int q = p - 2 * BATCH;
            u = sampled_user[q]; it = sampled_items[q];
        }
        const float sdu = sqrtf((float)deg[u]);
        const float2 a0 = ((const float2*)(user_emb + (size_t)u * EMB))[lane];
        const size_t ui = (size_t)u * EMBW + lane;
        const unsigned int u1 = e1[ui], u2 = e2[ui], u3 = e3[ui];
        const float ax = a0.x + sdu * (bfl(u1) + bfl(u2) + bfl(u3));
        const float ay = a0.y + sdu * (bfh(u1) + bfh(u2) + bfh(u3));
        const int itn = N_USERS + it;
        const float sdi = sqrtf((float)deg[itn]);
        const float2 b0 = ((const float2*)(item_emb + (size_t)it * EMB))[lane];
        const size_t ii = (size_t)itn * EMBW + lane;
        const unsigned int i1 = e1[ii], i2 = e2[ii], i3 = e3[ii];
        const float bx = b0.x + sdi * (bfl(i1) + bfl(i2) + bfl(i3));
        const float by = b0.y + sdi * (bfh(i1) + bfh(i2) + bfh(i3));
        float d = ax * bx + ay * by;
        #pragma unroll
        for (int off = 32; off > 0; off >>= 1) d += __shfl_down(d, off);
        if (lane == 0) {
            d *= (1.f / 16.f);                  // (acc/4)·(acc/4)
            const float pred = 1.f / (1.f + expf(-d));
            if (p < 2 * BATCH) {
                const float ls  = logsigmoidf(d);
                const float lsn = logsigmoidf(-d);
                s_bce   += (p < BATCH) ? -ls : -lsn;
                s_pred  += pred;
                s_plogp += pred * ls;
            } else {
                s_ul += pred;
            }
        }
    }
    __shared__ float red[4][4];
    if (lane == 0) {
        red[wid][0] = s_bce; red[wid][1] = s_pred;
        red[wid][2] = s_plogp; red[wid][3] = s_ul;
    }
    __syncthreads();
    if (threadIdx.x < 4) {
        const float v = red[0][threadIdx.x] + red[1][threadIdx.x]
                      + red[2][threadIdx.x] + red[3][threadIdx.x];
        atomicAdd(&sums[threadIdx.x], v);
    }
}

// ---------------- finalize ----------------------------------------------------
__global__ void finalize_kernel(const float* __restrict__ sums, float* __restrict__ out) {
    if (threadIdx.x == 0 && blockIdx.x == 0) {
        const float n = 2.f * BATCH;
        const float bce        = sums[0] / n;
        const float pred_avg   = sums[1] / n;
        const float plogp_avg  = sums[2] / n;
        const float predul_avg = sums[3] / n;
        const float info = ALPHA * (-pred_avg * logf(predul_avg)
                                    - (1.f - pred_avg) * logf(1.f - predul_avg))
                         + GAMMA * plogp_avg;
        out[0] = bce;
        out[1] = info;
    }
}

extern "C" void kernel_launch(void* const* d_in, const int* in_sizes, int n_in,
                              void* d_out, int out_size, void* d_ws, size_t ws_size,
                              hipStream_t stream) {
    const float* user_emb      = (const float*)d_in[0];
    const float* item_emb      = (const float*)d_in[1];
    const int*   edge_user     = (const int*)d_in[3];
    const int*   edge_item     = (const int*)d_in[4];
    const int*   users         = (const int*)d_in[5];
    const int*   pos_items     = (const int*)d_in[6];
    const int*   neg_items     = (const int*)d_in[7];
    const int*   sampled_user  = (const int*)d_in[8];
    const int*   sampled_items = (const int*)d_in[9];
    float* out = (float*)d_out;

    const size_t ebytes = (size_t)N_NODES * EMBW * sizeof(unsigned int); // 35.84 MB
    char* ws = (char*)d_ws;
    size_t off = 0;
    unsigned int* e0 = (unsigned int*)(ws + off); off += ebytes;
    unsigned int* e1 = (unsigned int*)(ws + off); off += ebytes;
    unsigned int* e2 = (unsigned int*)(ws + off); off += ebytes;
    unsigned int* e3 = (unsigned int*)(ws + off); off += ebytes;
    float* sums = (float*)(ws + off); off += 256;
    int*   deg       = (int*)(ws + off); off += (size_t)N_NODES * 4;
    int*   row_start = (int*)(ws + off); off += (size_t)(N_NODES + 1) * 4 + 252;
    int*   row_cur   = (int*)(ws + off); off += (size_t)N_NODES * 4;
    float* inv_sqrt  = (float*)(ws + off); off += (size_t)N_NODES * 4;
    unsigned char* row_grp = (unsigned char*)(ws + off); off += (size_t)N_NODES + 256;
    int*   csr_col   = (int*)(ws + off); off += (size_t)NNZ * 4;
    int*   bsum      = (int*)(ws + off); off += (size_t)SCAN_BLOCKS * 4;
    int*   boff      = (int*)(ws + off); off += (size_t)SCAN_BLOCKS * 4;

    hipMemsetAsync(deg, 0, (size_t)N_NODES * 4, stream);
    hipMemsetAsync(sums, 0, 4 * sizeof(float), stream);

    hist_kernel<<<2048, 256, 0, stream>>>(edge_user, edge_item, deg);
    partial_kernel<<<SCAN_BLOCKS, 256, 0, stream>>>(deg, bsum);
    scanb_kernel<<<1, 256, 0, stream>>>(bsum, boff, row_start);
    emit_kernel<<<SCAN_BLOCKS, 256, 0, stream>>>(deg, boff, row_start, row_cur,
                                                 inv_sqrt, row_grp);
    scatter_kernel<<<2048, 256, 0, stream>>>(edge_user, edge_item, row_grp,
                                             row_cur, csr_col);
    init_kernel<<<4096, 256, 0, stream>>>(user_emb, item_emb, inv_sqrt, e0);

    spmm_bf16_kernel<<<(N_NODES + 3) / 4, 256, 0, stream>>>(e0, e1, row_start,
                                                            csr_col, inv_sqrt);
    spmm_bf16_kernel<<<(N_NODES + 3) / 4, 256, 0, stream>>>(e1, e2, row_start,
                                                            csr_col, inv_sqrt);
    spmm_bf16_kernel<<<(N_NODES + 3) / 4, 256, 0, stream>>>(e2, e3, row_start,
                                                            csr_col, inv_sqrt);

    loss_kernel<<<512, 256, 0, stream>>>(user_emb, item_emb, e1, e2, e3, deg,
                                         users, pos_items, neg_items,
                                         sampled_user, sampled_items, sums);
    finalize_kernel<<<1, 1, 0, stream>>>(sums, out);
}

// Round 8
// 571.018 us; speedup vs baseline: 1.1917x; 1.0882x over previous
//
#include <hip/hip_runtime.h>
#include <math.h>

#define N_USERS 100000
#define N_ITEMS 40000
#define N_NODES (N_USERS + N_ITEMS)
#define EMB 128
#define EMBQ (EMB / 4)            /* 32 uints of packed 4x fp8 per row */
#define BATCH 8192
#define N_EDGES 1000000
#define NNZ (2 * N_EDGES)
#define N_LAYERS 3
#define ALPHA 0.1f
#define GAMMA 0.01f
#define NGRP 8                    /* one group per XCD (blockIdx % 8 heuristic) */
#define FP8_SCALE 32.0f           /* keep fp8 values in e4m3 normal range */
#define INV_FP8_SCALE (1.0f / FP8_SCALE)

#define SCAN_BLOCKS 256
#define SCAN_CHUNK ((N_NODES + SCAN_BLOCKS - 1) / SCAN_BLOCKS)   /* 547 */
#define SCAN_PER_THREAD ((SCAN_CHUNK + 255) / 256)               /* 3 */

typedef float f32x2 __attribute__((ext_vector_type(2)));

// ---------------- CSR build step 1: degree histogram (XCD-grouped) ------------
__global__ void hist_kernel(const int* __restrict__ edge_user,
                            const int* __restrict__ edge_item,
                            int* __restrict__ deg) {
    const int g = blockIdx.x & (NGRP - 1);
    int i = (blockIdx.x >> 3) * blockDim.x + threadIdx.x;
    const int stride = (gridDim.x >> 3) * blockDim.x;
    for (; i < NNZ; i += stride) {
        const int row = (i < N_EDGES) ? edge_user[i]
                                      : N_USERS + edge_item[i - N_EDGES];
        const int rg = (row * NGRP) / N_NODES;
        if (rg == g) atomicAdd(&deg[row], 1);
    }
}

// ---------------- CSR scan phase 1: per-block chunk sums ----------------------
__global__ void partial_kernel(const int* __restrict__ deg, int* __restrict__ bsum) {
    const int b = blockIdx.x;
    const int t = threadIdx.x;
    const int base = b * SCAN_CHUNK + t * SCAN_PER_THREAD;
    const int lim = min((b + 1) * SCAN_CHUNK, N_NODES);
    int s = 0;
    #pragma unroll
    for (int k = 0; k < SCAN_PER_THREAD; ++k) {
        const int i = base + k;
        if (i < lim) s += deg[i];
    }
    __shared__ int red[4];
    #pragma unroll
    for (int off = 32; off > 0; off >>= 1) s += __shfl_down(s, off);
    const int lane = t & 63, wid = t >> 6;
    if (lane == 0) red[wid] = s;
    __syncthreads();
    if (t == 0) bsum[b] = red[0] + red[1] + red[2] + red[3];
}

// ---------------- CSR scan phase 2: scan 256 block sums -----------------------
__global__ void scanb_kernel(const int* __restrict__ bsum, int* __restrict__ boff,
                             int* __restrict__ row_start) {
    const int t = threadIdx.x;        // 256 threads
    const int lane = t & 63, wid = t >> 6;
    const int v = bsum[t];
    int x = v;
    #pragma unroll
    for (int off = 1; off < 64; off <<= 1) {
        const int y = __shfl_up(x, off);
        if (lane >= off) x += y;
    }
    __shared__ int wtot[4];
    if (lane == 63) wtot[wid] = x;
    __syncthreads();
    int wo = 0;
    for (int k = 0; k < wid; ++k) wo += wtot[k];
    boff[t] = wo + x - v;
    if (t == 255) row_start[N_NODES] = wo + x;   // == NNZ
}

// -------- CSR scan phase 3: emit row_start/row_cur + inv_sqrt + row_grp -------
__global__ void emit_kernel(const int* __restrict__ deg, const int* __restrict__ boff,
                            int* __restrict__ row_start, int* __restrict__ row_cur,
                            float* __restrict__ inv_sqrt,
                            unsigned char* __restrict__ row_grp) {
    const int b = blockIdx.x;
    const int t = threadIdx.x;
    const int lane = t & 63, wid = t >> 6;
    const int base = b * SCAN_CHUNK + t * SCAN_PER_THREAD;
    const int lim = min((b + 1) * SCAN_CHUNK, N_NODES);
    int d[SCAN_PER_THREAD];
    int s = 0;
    #pragma unroll
    for (int k = 0; k < SCAN_PER_THREAD; ++k) {
        const int i = base + k;
        d[k] = (i < lim) ? deg[i] : 0;
        s += d[k];
    }
    int x = s;
    #pragma unroll
    for (int off = 1; off < 64; off <<= 1) {
        const int y = __shfl_up(x, off);
        if (lane >= off) x += y;
    }
    __shared__ int wtot[4];
    if (lane == 63) wtot[wid] = x;
    __syncthreads();
    int wo = boff[b];
    for (int k = 0; k < wid; ++k) wo += wtot[k];
    int p = wo + x - s;
    #pragma unroll
    for (int k = 0; k < SCAN_PER_THREAD; ++k) {
        const int i = base + k;
        if (i < lim) {
            row_start[i] = p;
            row_cur[i]   = p;
            inv_sqrt[i]  = (d[k] > 0) ? (1.0f / sqrtf((float)d[k])) : 0.0f;
            row_grp[i]   = (unsigned char)(((long long)p * NGRP) / NNZ);
            p += d[k];
        }
    }
}

// ---------------- CSR build: scatter edge cols (XCD-grouped) ------------------
__global__ void scatter_kernel(const int* __restrict__ edge_user,
                               const int* __restrict__ edge_item,
                               const unsigned char* __restrict__ row_grp,
                               int* __restrict__ row_cur,
                               int* __restrict__ csr_col) {
    const int g = blockIdx.x & (NGRP - 1);
    int i = (blockIdx.x >> 3) * blockDim.x + threadIdx.x;
    const int stride = (gridDim.x >> 3) * blockDim.x;
    for (; i < NNZ; i += stride) {
        int row, col;
        if (i < N_EDGES) { row = edge_user[i];            col = N_USERS + edge_item[i]; }
        else { const int e = i - N_EDGES; row = N_USERS + edge_item[e]; col = edge_user[e]; }
        if (row_grp[row] != g) continue;
        const int pos = atomicAdd(&row_cur[row], 1);
        csr_col[pos] = col;
    }
}

// ---------------- init: e0 = fp8(S * inv_sqrt[node] * x0) ---------------------
__global__ void init_kernel(const float* __restrict__ user_emb,
                            const float* __restrict__ item_emb,
                            const float* __restrict__ inv_sqrt,
                            unsigned int* __restrict__ e0) {
    const int total = N_NODES * EMBQ;
    int i = blockIdx.x * blockDim.x + threadIdx.x;
    const int stride = gridDim.x * blockDim.x;
    for (; i < total; i += stride) {
        const int node = i >> 5;           // /EMBQ
        const int q    = i & 31;
        float4 v;
        if (node < N_USERS)
            v = ((const float4*)(user_emb + (size_t)node * EMB))[q];
        else
            v = ((const float4*)(item_emb + (size_t)(node - N_USERS) * EMB))[q];
        const float n = FP8_SCALE * inv_sqrt[node];
        int pk = __builtin_amdgcn_cvt_pk_fp8_f32(n * v.x, n * v.y, 0, false);
        pk = __builtin_amdgcn_cvt_pk_fp8_f32(n * v.z, n * v.w, pk, true);
        e0[i] = (unsigned int)pk;
    }
}

// ---------------- SpMM (fp8 rows): w'[r] = n[r]^2 * sum w[c] ------------------
// wave per row; 2 edges per iteration: lanes 0-31 even edge, 32-63 odd edge;
// each lane covers 4 dims (1 uint of 4 fp8). shfl combines halves.
__global__ void spmm_fp8_kernel(const unsigned int* __restrict__ cur,
                                unsigned int* __restrict__ nxt,
                                const int* __restrict__ row_start,
                                const int* __restrict__ csr_col,
                                const float* __restrict__ inv_sqrt) {
    const int lane = threadIdx.x & 63;
    const int half = lane >> 5;
    const int sub  = lane & 31;
    const int w = blockIdx.x * (blockDim.x >> 6) + (threadIdx.x >> 6);
    if (w >= N_NODES) return;
    const int beg = row_start[w];
    const int end = row_start[w + 1];
    float s0 = 0.f, s1 = 0.f, s2 = 0.f, s3 = 0.f;
    for (int j = beg + half; j < end; j += 2) {
        const int c = csr_col[j];
        const unsigned int v = cur[(size_t)c * EMBQ + sub];
        const f32x2 lo = __builtin_amdgcn_cvt_pk_f32_fp8((int)v, false);
        const f32x2 hi = __builtin_amdgcn_cvt_pk_f32_fp8((int)v, true);
        s0 += lo.x; s1 += lo.y; s2 += hi.x; s3 += hi.y;
    }
    s0 += __shfl_down(s0, 32);
    s1 += __shfl_down(s1, 32);
    s2 += __shfl_down(s2, 32);
    s3 += __shfl_down(s3, 32);
    if (half == 0) {
        const float n = inv_sqrt[w];
        const float sc = n * n;
        int pk = __builtin_amdgcn_cvt_pk_fp8_f32(sc * s0, sc * s1, 0, false);
        pk = __builtin_amdgcn_cvt_pk_fp8_f32(sc * s2, sc * s3, pk, true);
        nxt[(size_t)w * EMBQ + sub] = (unsigned int)pk;
    }
}

__device__ inline float logsigmoidf(float x) {
    return (x >= 0.f) ? -log1pf(expf(-x)) : (x - log1pf(expf(x)));
}

// ---------------- fused losses ------------------------------------------------
// acc-row on the fly: x0(fp32) + sqrt(deg)/S * (w1+w2+w3 fp8), dot, /16.
__global__ void loss_kernel(const float* __restrict__ user_emb,
                            const float* __restrict__ item_emb,
                            const unsigned short* __restrict__ e1,
                            const unsigned short* __restrict__ e2,
                            const unsigned short* __restrict__ e3,
                            const int* __restrict__ deg,
                            const int* __restrict__ users,
                            const int* __restrict__ pos_items,
                            const int* __restrict__ neg_items,
                            const int* __restrict__ sampled_user,
                            const int* __restrict__ sampled_items,
                            float* __restrict__ sums) {
    const int lane = threadIdx.x & 63;     // dims 2*lane, 2*lane+1
    const int wid  = threadIdx.x >> 6;     // 0..3
    const int gw   = blockIdx.x * 4 + wid;
    const int nw   = gridDim.x * 4;
    float s_bce = 0.f, s_pred = 0.f, s_plogp = 0.f, s_ul = 0.f;
    for (int p = gw; p < 4 * BATCH; p += nw) {
        int u, it;
        if (p < 2 * BATCH) {
            if (p < BATCH) { u = users[p];          it = pos_items[p]; }
            else           { u = users[p - BATCH];  it = neg_items[p - BATCH]; }
        } else {
            const int q = p - 2 * BATCH;
            u = sampled_user[q]; it = sampled_items[q];
        }
        const float sdu = sqrtf((float)deg[u]) * INV_FP8_SCALE;
        const float2 a0 = ((const float2*)(user_emb + (size_t)u * EMB))[lane];
        const size_t ui = (size_t)u * 64 + lane;
        const f32x2 u1 = __builtin_amdgcn_cvt_pk_f32_fp8((int)e1[ui], false);
        const f32x2 u2 = __builtin_amdgcn_cvt_pk_f32_fp8((int)e2[ui], false);
        const f32x2 u3 = __builtin_amdgcn_cvt_pk_f32_fp8((int)e3[ui], false);
        const float ax = a0.x + sdu * (u1.x + u2.x + u3.x);
        const float ay = a0.y + sdu * (u1.y + u2.y + u3.y);
        const int itn = N_USERS + it;
        const float sdi = sqrtf((float)deg[itn]) * INV_FP8_SCALE;
        const float2 b0 = ((const float2*)(item_emb + (size_t)it * EMB))[lane];
        const size_t ii = (size_t)itn * 64 + lane;
        const f32x2 i1 = __builtin_amdgcn_cvt_pk_f32_fp8((int)e1[ii], false);
        const f32x2 i2 = __builtin_amdgcn_cvt_pk_f32_fp8((int)e2[ii], false);
        const f32x2 i3 = __builtin_amdgcn_cvt_pk_f32_fp8((int)e3[ii], false);
        const float bx = b0.x + sdi * (i1.x + i2.x + i3.x);
        const float by = b0.y + sdi * (i1.y + i2.y + i3.y);
        float d = ax * bx + ay * by;
        #pragma unroll
        for (int off = 32; off > 0; off >>= 1) d += __shfl_down(d, off);
        if (lane == 0) {
            d *= (1.f / 16.f);                  // (acc/4)·(acc/4)
            const float pred = 1.f / (1.f + expf(-d));
            if (p < 2 * BATCH) {
                const float ls  = logsigmoidf(d);
                const float lsn = logsigmoidf(-d);
                s_bce   += (p < BATCH) ? -ls : -lsn;
                s_pred  += pred;
                s_plogp += pred * ls;
            } else {
                s_ul += pred;
            }
        }
    }
    __shared__ float red[4][4];
    if (lane == 0) {
        red[wid][0] = s_bce; red[wid][1] = s_pred;
        red[wid][2] = s_plogp; red[wid][3] = s_ul;
    }
    __syncthreads();
    if (threadIdx.x < 4) {
        const float v = red[0][threadIdx.x] + red[1][threadIdx.x]
                      + red[2][threadIdx.x] + red[3][threadIdx.x];
        atomicAdd(&sums[threadIdx.x], v);
    }
}

// ---------------- finalize ----------------------------------------------------
__global__ void finalize_kernel(const float* __restrict__ sums, float* __restrict__ out) {
    if (threadIdx.x == 0 && blockIdx.x == 0) {
        const float n = 2.f * BATCH;
        const float bce        = sums[0] / n;
        const float pred_avg   = sums[1] / n;
        const float plogp_avg  = sums[2] / n;
        const float predul_avg = sums[3] / n;
        const float info = ALPHA * (-pred_avg * logf(predul_avg)
                                    - (1.f - pred_avg) * logf(1.f - predul_avg))
                         + GAMMA * plogp_avg;
        out[0] = bce;
        out[1] = info;
    }
}

extern "C" void kernel_launch(void* const* d_in, const int* in_sizes, int n_in,
                              void* d_out, int out_size, void* d_ws, size_t ws_size,
                              hipStream_t stream) {
    const float* user_emb      = (const float*)d_in[0];
    const float* item_emb      = (const float*)d_in[1];
    const int*   edge_user     = (const int*)d_in[3];
    const int*   edge_item     = (const int*)d_in[4];
    const int*   users         = (const int*)d_in[5];
    const int*   pos_items     = (const int*)d_in[6];
    const int*   neg_items     = (const int*)d_in[7];
    const int*   sampled_user  = (const int*)d_in[8];
    const int*   sampled_items = (const int*)d_in[9];
    float* out = (float*)d_out;

    const size_t ebytes = (size_t)N_NODES * EMBQ * sizeof(unsigned int); // 17.92 MB
    char* ws = (char*)d_ws;
    size_t off = 0;
    unsigned int* e0 = (unsigned int*)(ws + off); off += ebytes;
    unsigned int* e1 = (unsigned int*)(ws + off); off += ebytes;
    unsigned int* e2 = (unsigned int*)(ws + off); off += ebytes;
    unsigned int* e3 = (unsigned int*)(ws + off); off += ebytes;
    float* sums = (float*)(ws + off); off += 256;
    int*   deg       = (int*)(ws + off); off += (size_t)N_NODES * 4;
    int*   row_start = (int*)(ws + off); off += (size_t)(N_NODES + 1) * 4 + 252;
    int*   row_cur   = (int*)(ws + off); off += (size_t)N_NODES * 4;
    float* inv_sqrt  = (float*)(ws + off); off += (size_t)N_NODES * 4;
    unsigned char* row_grp = (unsigned char*)(ws + off); off += (size_t)N_NODES + 256;
    int*   csr_col   = (int*)(ws + off); off += (size_t)NNZ * 4;
    int*   bsum      = (int*)(ws + off); off += (size_t)SCAN_BLOCKS * 4;
    int*   boff      = (int*)(ws + off); off += (size_t)SCAN_BLOCKS * 4;

    hipMemsetAsync(deg, 0, (size_t)N_NODES * 4, stream);
    hipMemsetAsync(sums, 0, 4 * sizeof(float), stream);

    hist_kernel<<<2048, 256, 0, stream>>>(edge_user, edge_item, deg);
    partial_kernel<<<SCAN_BLOCKS, 256, 0, stream>>>(deg, bsum);
    scanb_kernel<<<1, 256, 0, stream>>>(bsum, boff, row_start);
    emit_kernel<<<SCAN_BLOCKS, 256, 0, stream>>>(deg, boff, row_start, row_cur,
                                                 inv_sqrt, row_grp);
    scatter_kernel<<<2048, 256, 0, stream>>>(edge_user, edge_item, row_grp,
                                             row_cur, csr_col);
    init_kernel<<<4096, 256, 0, stream>>>(user_emb, item_emb, inv_sqrt, e0);

    spmm_fp8_kernel<<<(N_NODES + 3) / 4, 256, 0, stream>>>(e0, e1, row_start,
                                                           csr_col, inv_sqrt);
    spmm_fp8_kernel<<<(N_NODES + 3) / 4, 256, 0, stream>>>(e1, e2, row_start,
                                                           csr_col, inv_sqrt);
    spmm_fp8_kernel<<<(N_NODES + 3) / 4, 256, 0, stream>>>(e2, e3, row_start,
                                                           csr_col, inv_sqrt);

    loss_kernel<<<512, 256, 0, stream>>>(user_emb, item_emb,
                                         (const unsigned short*)e1,
                                         (const unsigned short*)e2,
                                         (const unsigned short*)e3,
                                         deg, users, pos_items, neg_items,
                                         sampled_user, sampled_items, sums);
    finalize_kernel<<<1, 1, 0, stream>>>(sums, out);
}

// Round 9
// 428.979 us; speedup vs baseline: 1.5863x; 1.3311x over previous
//
#include <hip/hip_runtime.h>
#include <math.h>

#define N_USERS 100000
#define N_ITEMS 40000
#define N_NODES (N_USERS + N_ITEMS)
#define EMB 128
#define EMBQ (EMB / 4)            /* 32 uints of packed 4x fp8 per row */
#define EMBH (EMB / 2)            /* 64 uints of packed 2x bf16 per row */
#define BATCH 8192
#define N_EDGES 1000000
#define NNZ (2 * N_EDGES)
#define NNZ_PAD_MAX (NNZ + 8 * N_NODES)
#define N_LAYERS 3
#define ALPHA 0.1f
#define GAMMA 0.01f
#define NGRP 8                    /* one group per XCD (blockIdx % 8 heuristic) */
#define FP8_SCALE 32.0f           /* keep fp8 values in e4m3 normal range */
#define INV_FP8_SCALE (1.0f / FP8_SCALE)

#define SCAN_BLOCKS 256
#define SCAN_CHUNK ((N_NODES + SCAN_BLOCKS - 1) / SCAN_BLOCKS)   /* 547 */
#define SCAN_PER_THREAD ((SCAN_CHUNK + 255) / 256)               /* 3 */

typedef float f32x2 __attribute__((ext_vector_type(2)));

// ---------- bf16 pack/unpack (RNE) -------------------------------------------
__device__ inline unsigned int f2bf(float x) {
    const unsigned int b = __float_as_uint(x);
    return (b + 0x7FFFu + ((b >> 16) & 1u)) >> 16;
}
__device__ inline float bfl(unsigned int w) { return __uint_as_float(w << 16); }
__device__ inline float bfh(unsigned int w) { return __uint_as_float(w & 0xFFFF0000u); }

// ---------------- CSR build step 1: degree histogram (XCD-grouped) ------------
__global__ void hist_kernel(const int* __restrict__ edge_user,
                            const int* __restrict__ edge_item,
                            int* __restrict__ deg) {
    const int g = blockIdx.x & (NGRP - 1);
    int i = (blockIdx.x >> 3) * blockDim.x + threadIdx.x;
    const int stride = (gridDim.x >> 3) * blockDim.x;
    for (; i < NNZ; i += stride) {
        const int row = (i < N_EDGES) ? edge_user[i]
                                      : N_USERS + edge_item[i - N_EDGES];
        const int rg = (row * NGRP) / N_NODES;
        if (rg == g) atomicAdd(&deg[row], 1);
    }
}

// ---------------- CSR scan phase 1: per-block sums of PADDED degrees ----------
__global__ void partial_kernel(const int* __restrict__ deg, int* __restrict__ bsum) {
    const int b = blockIdx.x;
    const int t = threadIdx.x;
    const int base = b * SCAN_CHUNK + t * SCAN_PER_THREAD;
    const int lim = min((b + 1) * SCAN_CHUNK, N_NODES);
    int s = 0;
    #pragma unroll
    for (int k = 0; k < SCAN_PER_THREAD; ++k) {
        const int i = base + k;
        if (i < lim) s += (deg[i] + 7) & ~7;
    }
    __shared__ int red[4];
    #pragma unroll
    for (int off = 32; off > 0; off >>= 1) s += __shfl_down(s, off);
    const int lane = t & 63, wid = t >> 6;
    if (lane == 0) red[wid] = s;
    __syncthreads();
    if (t == 0) bsum[b] = red[0] + red[1] + red[2] + red[3];
}

// ---------------- CSR scan phase 2: scan 256 block sums -----------------------
__global__ void scanb_kernel(const int* __restrict__ bsum, int* __restrict__ boff,
                             int* __restrict__ row_start) {
    const int t = threadIdx.x;        // 256 threads
    const int lane = t & 63, wid = t >> 6;
    const int v = bsum[t];
    int x = v;
    #pragma unroll
    for (int off = 1; off < 64; off <<= 1) {
        const int y = __shfl_up(x, off);
        if (lane >= off) x += y;
    }
    __shared__ int wtot[4];
    if (lane == 63) wtot[wid] = x;
    __syncthreads();
    int wo = 0;
    for (int k = 0; k < wid; ++k) wo += wtot[k];
    boff[t] = wo + x - v;
    if (t == 255) row_start[N_NODES] = wo + x;   // padded nnz total
}

// -- CSR scan phase 3: emit row_start/row_cur/inv_sqrt/row_grp + pad fill ------
__global__ void emit_kernel(const int* __restrict__ deg, const int* __restrict__ boff,
                            int* __restrict__ row_start, int* __restrict__ row_cur,
                            float* __restrict__ inv_sqrt,
                            unsigned char* __restrict__ row_grp,
                            int* __restrict__ csr_col) {
    const int b = blockIdx.x;
    const int t = threadIdx.x;
    const int lane = t & 63, wid = t >> 6;
    const int base = b * SCAN_CHUNK + t * SCAN_PER_THREAD;
    const int lim = min((b + 1) * SCAN_CHUNK, N_NODES);
    const int tot = row_start[N_NODES];          // written by scanb
    int d[SCAN_PER_THREAD], dp[SCAN_PER_THREAD];
    int s = 0;
    #pragma unroll
    for (int k = 0; k < SCAN_PER_THREAD; ++k) {
        const int i = base + k;
        d[k]  = (i < lim) ? deg[i] : 0;
        dp[k] = (d[k] + 7) & ~7;
        s += dp[k];
    }
    int x = s;
    #pragma unroll
    for (int off = 1; off < 64; off <<= 1) {
        const int y = __shfl_up(x, off);
        if (lane >= off) x += y;
    }
    __shared__ int wtot[4];
    if (lane == 63) wtot[wid] = x;
    __syncthreads();
    int wo = boff[b];
    for (int k = 0; k < wid; ++k) wo += wtot[k];
    int p = wo + x - s;
    #pragma unroll
    for (int k = 0; k < SCAN_PER_THREAD; ++k) {
        const int i = base + k;
        if (i < lim) {
            row_start[i] = p;
            row_cur[i]   = p;
            inv_sqrt[i]  = (d[k] > 0) ? (1.0f / sqrtf((float)d[k])) : 0.0f;
            row_grp[i]   = (unsigned char)(((long long)p * NGRP) / tot);
            for (int q = d[k]; q < dp[k]; ++q) csr_col[p + q] = N_NODES; // dummy
            p += dp[k];
        }
    }
}

// ---------------- CSR build: scatter edge cols (XCD-grouped) ------------------
__global__ void scatter_kernel(const int* __restrict__ edge_user,
                               const int* __restrict__ edge_item,
                               const unsigned char* __restrict__ row_grp,
                               int* __restrict__ row_cur,
                               int* __restrict__ csr_col) {
    const int g = blockIdx.x & (NGRP - 1);
    int i = (blockIdx.x >> 3) * blockDim.x + threadIdx.x;
    const int stride = (gridDim.x >> 3) * blockDim.x;
    for (; i < NNZ; i += stride) {
        int row, col;
        if (i < N_EDGES) { row = edge_user[i];            col = N_USERS + edge_item[i]; }
        else { const int e = i - N_EDGES; row = N_USERS + edge_item[e]; col = edge_user[e]; }
        if (row_grp[row] != g) continue;
        const int pos = atomicAdd(&row_cur[row], 1);
        csr_col[pos] = col;
    }
}

// ---------------- zero the dummy row (N_NODES) of all 4 fp8 buffers -----------
__global__ void zero_rows_kernel(unsigned int* __restrict__ e0,
                                 unsigned int* __restrict__ e1,
                                 unsigned int* __restrict__ e2,
                                 unsigned int* __restrict__ e3) {
    const int t = threadIdx.x;   // 128 threads
    unsigned int* bufs[4] = {e0, e1, e2, e3};
    bufs[t >> 5][(size_t)N_NODES * EMBQ + (t & 31)] = 0u;
}

// -------- init: e0 = fp8(S * inv_sqrt * x0); x0b = bf16(x0) -------------------
__global__ void init_kernel(const float* __restrict__ user_emb,
                            const float* __restrict__ item_emb,
                            const float* __restrict__ inv_sqrt,
                            unsigned int* __restrict__ e0,
                            unsigned int* __restrict__ x0b) {
    const int total = N_NODES * EMBQ;
    int i = blockIdx.x * blockDim.x + threadIdx.x;
    const int stride = gridDim.x * blockDim.x;
    for (; i < total; i += stride) {
        const int node = i >> 5;           // /EMBQ
        const int q    = i & 31;
        float4 v;
        if (node < N_USERS)
            v = ((const float4*)(user_emb + (size_t)node * EMB))[q];
        else
            v = ((const float4*)(item_emb + (size_t)(node - N_USERS) * EMB))[q];
        const float n = FP8_SCALE * inv_sqrt[node];
        int pk = __builtin_amdgcn_cvt_pk_fp8_f32(n * v.x, n * v.y, 0, false);
        pk = __builtin_amdgcn_cvt_pk_fp8_f32(n * v.z, n * v.w, pk, true);
        e0[i] = (unsigned int)pk;
        const size_t xb = (size_t)node * EMBH + q * 2;
        x0b[xb]     = f2bf(v.x) | (f2bf(v.y) << 16);
        x0b[xb + 1] = f2bf(v.z) | (f2bf(v.w) << 16);
    }
}

// ---------------- SpMM (fp8, padded CSR): w'[r] = n[r]^2 * sum w[c] -----------
// wave per row; halves take alternate edges; unroll 4 => 4 col loads + 4
// gathers independent and in flight (breaks the col->gather latency chain).
__global__ void spmm_fp8_kernel(const unsigned int* __restrict__ cur,
                                unsigned int* __restrict__ nxt,
                                const int* __restrict__ row_start,
                                const int* __restrict__ csr_col,
                                const float* __restrict__ inv_sqrt) {
    const int lane = threadIdx.x & 63;
    const int half = lane >> 5;
    const int sub  = lane & 31;
    const int w = blockIdx.x * (blockDim.x >> 6) + (threadIdx.x >> 6);
    if (w >= N_NODES) return;
    const int beg = row_start[w];
    const int end = row_start[w + 1];       // padded: (end-beg) % 8 == 0
    float s0 = 0.f, s1 = 0.f, s2 = 0.f, s3 = 0.f;
    for (int j = beg + half; j < end; j += 8) {
        const int c0 = csr_col[j];
        const int c1 = csr_col[j + 2];
        const int c2 = csr_col[j + 4];
        const int c3 = csr_col[j + 6];
        const unsigned int v0 = cur[(size_t)c0 * EMBQ + sub];
        const unsigned int v1 = cur[(size_t)c1 * EMBQ + sub];
        const unsigned int v2 = cur[(size_t)c2 * EMBQ + sub];
        const unsigned int v3 = cur[(size_t)c3 * EMBQ + sub];
        const f32x2 l0 = __builtin_amdgcn_cvt_pk_f32_fp8((int)v0, false);
        const f32x2 h0 = __builtin_amdgcn_cvt_pk_f32_fp8((int)v0, true);
        const f32x2 l1 = __builtin_amdgcn_cvt_pk_f32_fp8((int)v1, false);
        const f32x2 h1 = __builtin_amdgcn_cvt_pk_f32_fp8((int)v1, true);
        const f32x2 l2 = __builtin_amdgcn_cvt_pk_f32_fp8((int)v2, false);
        const f32x2 h2 = __builtin_amdgcn_cvt_pk_f32_fp8((int)v2, true);
        const f32x2 l3 = __builtin_amdgcn_cvt_pk_f32_fp8((int)v3, false);
        const f32x2 h3 = __builtin_amdgcn_cvt_pk_f32_fp8((int)v3, true);
        s0 += (l0.x + l1.x) + (l2.x + l3.x);
        s1 += (l0.y + l1.y) + (l2.y + l3.y);
        s2 += (h0.x + h1.x) + (h2.x + h3.x);
        s3 += (h0.y + h1.y) + (h2.y + h3.y);
    }
    s0 += __shfl_down(s0, 32);
    s1 += __shfl_down(s1, 32);
    s2 += __shfl_down(s2, 32);
    s3 += __shfl_down(s3, 32);
    if (half == 0) {
        const float n = inv_sqrt[w];
        const float sc = n * n;
        int pk = __builtin_amdgcn_cvt_pk_fp8_f32(sc * s0, sc * s1, 0, false);
        pk = __builtin_amdgcn_cvt_pk_fp8_f32(sc * s2, sc * s3, pk, true);
        nxt[(size_t)w * EMBQ + sub] = (unsigned int)pk;
    }
}

__device__ inline float logsigmoidf(float x) {
    return (x >= 0.f) ? -log1pf(expf(-x)) : (x - log1pf(expf(x)));
}

// ---------------- fused losses ------------------------------------------------
// acc-row on the fly: x0(bf16) + sqrt(deg)/S * (w1+w2+w3 fp8), dot, /16.
__global__ void loss_kernel(const unsigned int* __restrict__ x0b,
                            const unsigned short* __restrict__ e1,
                            const unsigned short* __restrict__ e2,
                            const unsigned short* __restrict__ e3,
                            const int* __restrict__ deg,
                            const int* __restrict__ users,
                            const int* __restrict__ pos_items,
                            const int* __restrict__ neg_items,
                            const int* __restrict__ sampled_user,
                            const int* __restrict__ sampled_items,
                            float* __restrict__ sums) {
    const int lane = threadIdx.x & 63;     // dims 2*lane, 2*lane+1
    const int wid  = threadIdx.x >> 6;     // 0..3
    const int gw   = blockIdx.x * 4 + wid;
    const int nw   = gridDim.x * 4;
    float s_bce = 0.f, s_pred = 0.f, s_plogp = 0.f, s_ul = 0.f;
    for (int p = gw; p < 4 * BATCH; p += nw) {
        int u, it;
        if (p < 2 * BATCH) {
            if (p < BATCH) { u = users[p];          it = pos_items[p]; }
            else           { u = users[p - BATCH];  it = neg_items[p - BATCH]; }
        } else {
            const int q = p - 2 * BATCH;
            u = sampled_user[q]; it = sampled_items[q];
        }
        const float sdu = sqrtf((float)deg[u]) * INV_FP8_SCALE;
        const unsigned int a0 = x0b[(size_t)u * EMBH + lane];
        const size_t ui = (size_t)u * 64 + lane;
        const f32x2 u1 = __builtin_amdgcn_cvt_pk_f32_fp8((int)e1[ui], false);
        const f32x2 u2 = __builtin_amdgcn_cvt_pk_f32_fp8((int)e2[ui], false);
        const f32x2 u3 = __builtin_amdgcn_cvt_pk_f32_fp8((int)e3[ui], false);
        const float ax = bfl(a0) + sdu * (u1.x + u2.x + u3.x);
        const float ay = bfh(a0) + sdu * (u1.y + u2.y + u3.y);
        const int itn = N_USERS + it;
        const float sdi = sqrtf((float)deg[itn]) * INV_FP8_SCALE;
        const unsigned int b0 = x0b[(size_t)itn * EMBH + lane];
        const size_t ii = (size_t)itn * 64 + lane;
        const f32x2 i1 = __builtin_amdgcn_cvt_pk_f32_fp8((int)e1[ii], false);
        const f32x2 i2 = __builtin_amdgcn_cvt_pk_f32_fp8((int)e2[ii], false);
        const f32x2 i3 = __builtin_amdgcn_cvt_pk_f32_fp8((int)e3[ii], false);
        const float bx = bfl(b0) + sdi * (i1.x + i2.x + i3.x);
        const float by = bfh(b0) + sdi * (i1.y + i2.y + i3.y);
        float d = ax * bx + ay * by;
        #pragma unroll
        for (int off = 32; off > 0; off >>= 1) d += __shfl_down(d, off);
        if (lane == 0) {
            d *= (1.f / 16.f);                  // (acc/4)·(acc/4)
            const float pred = 1.f / (1.f + expf(-d));
            if (p < 2 * BATCH) {
                const float ls  = logsigmoidf(d);
                const float lsn = logsigmoidf(-d);
                s_bce   += (p < BATCH) ? -ls : -lsn;
                s_pred  += pred;
                s_plogp += pred * ls;
            } else {
                s_ul += pred;
            }
        }
    }
    __shared__ float red[4][4];
    if (lane == 0) {
        red[wid][0] = s_bce; red[wid][1] = s_pred;
        red[wid][2] = s_plogp; red[wid][3] = s_ul;
    }
    __syncthreads();
    if (threadIdx.x < 4) {
        const float v = red[0][threadIdx.x] + red[1][threadIdx.x]
                      + red[2][threadIdx.x] + red[3][threadIdx.x];
        atomicAdd(&sums[threadIdx.x], v);
    }
}

// ---------------- finalize ----------------------------------------------------
__global__ void finalize_kernel(const float* __restrict__ sums, float* __restrict__ out) {
    if (threadIdx.x == 0 && blockIdx.x == 0) {
        const float n = 2.f * BATCH;
        const float bce        = sums[0] / n;
        const float pred_avg   = sums[1] / n;
        const float plogp_avg  = sums[2] / n;
        const float predul_avg = sums[3] / n;
        const float info = ALPHA * (-pred_avg * logf(predul_avg)
                                    - (1.f - pred_avg) * logf(1.f - predul_avg))
                         + GAMMA * plogp_avg;
        out[0] = bce;
        out[1] = info;
    }
}

extern "C" void kernel_launch(void* const* d_in, const int* in_sizes, int n_in,
                              void* d_out, int out_size, void* d_ws, size_t ws_size,
                              hipStream_t stream) {
    const float* user_emb      = (const float*)d_in[0];
    const float* item_emb      = (const float*)d_in[1];
    const int*   edge_user     = (const int*)d_in[3];
    const int*   edge_item     = (const int*)d_in[4];
    const int*   users         = (const int*)d_in[5];
    const int*   pos_items     = (const int*)d_in[6];
    const int*   neg_items     = (const int*)d_in[7];
    const int*   sampled_user  = (const int*)d_in[8];
    const int*   sampled_items = (const int*)d_in[9];
    float* out = (float*)d_out;

    const size_t ebytes = (size_t)(N_NODES + 1) * EMBQ * sizeof(unsigned int); // 17.9 MB
    char* ws = (char*)d_ws;
    size_t off = 0;
    unsigned int* e0  = (unsigned int*)(ws + off); off += ebytes;
    unsigned int* e1  = (unsigned int*)(ws + off); off += ebytes;
    unsigned int* e2  = (unsigned int*)(ws + off); off += ebytes;
    unsigned int* e3  = (unsigned int*)(ws + off); off += ebytes;
    unsigned int* x0b = (unsigned int*)(ws + off); off += (size_t)N_NODES * EMBH * 4;
    float* sums = (float*)(ws + off); off += 256;
    int*   deg       = (int*)(ws + off); off += (size_t)N_NODES * 4;
    int*   row_start = (int*)(ws + off); off += (size_t)(N_NODES + 1) * 4 + 252;
    int*   row_cur   = (int*)(ws + off); off += (size_t)N_NODES * 4;
    float* inv_sqrt  = (float*)(ws + off); off += (size_t)N_NODES * 4;
    unsigned char* row_grp = (unsigned char*)(ws + off); off += (size_t)N_NODES + 256;
    int*   csr_col   = (int*)(ws + off); off += (size_t)NNZ_PAD_MAX * 4;
    int*   bsum      = (int*)(ws + off); off += (size_t)SCAN_BLOCKS * 4;
    int*   boff      = (int*)(ws + off); off += (size_t)SCAN_BLOCKS * 4;

    hipMemsetAsync(deg, 0, (size_t)N_NODES * 4, stream);
    hipMemsetAsync(sums, 0, 4 * sizeof(float), stream);

    hist_kernel<<<2048, 256, 0, stream>>>(edge_user, edge_item, deg);
    partial_kernel<<<SCAN_BLOCKS, 256, 0, stream>>>(deg, bsum);
    scanb_kernel<<<1, 256, 0, stream>>>(bsum, boff, row_start);
    emit_kernel<<<SCAN_BLOCKS, 256, 0, stream>>>(deg, boff, row_start, row_cur,
                                                 inv_sqrt, row_grp, csr_col);
    scatter_kernel<<<2048, 256, 0, stream>>>(edge_user, edge_item, row_grp,
                                             row_cur, csr_col);
    zero_rows_kernel<<<1, 128, 0, stream>>>(e0, e1, e2, e3);
    init_kernel<<<4096, 256, 0, stream>>>(user_emb, item_emb, inv_sqrt, e0, x0b);

    spmm_fp8_kernel<<<(N_NODES + 3) / 4, 256, 0, stream>>>(e0, e1, row_start,
                                                           csr_col, inv_sqrt);
    spmm_fp8_kernel<<<(N_NODES + 3) / 4, 256, 0, stream>>>(e1, e2, row_start,
                                                           csr_col, inv_sqrt);
    spmm_fp8_kernel<<<(N_NODES + 3) / 4, 256, 0, stream>>>(e2, e3, row_start,
                                                           csr_col, inv_sqrt);

    loss_kernel<<<512, 256, 0, stream>>>(x0b,
                                         (const unsigned short*)e1,
                                         (const unsigned short*)e2,
                                         (const unsigned short*)e3,
                                         deg, users, pos_items, neg_items,
                                         sampled_user, sampled_items, sums);
    finalize_kernel<<<1, 1, 0, stream>>>(sums, out);
}

// Round 10
// 427.586 us; speedup vs baseline: 1.5915x; 1.0033x over previous
//
#include <hip/hip_runtime.h>
#include <math.h>

#define N_USERS 100000
#define N_ITEMS 40000
#define N_NODES (N_USERS + N_ITEMS)
#define EMB 128
#define EMBQ (EMB / 4)            /* 32 uints of packed 4x fp8 per row */
#define EMBH (EMB / 2)            /* 64 uints of packed 2x bf16 per row */
#define BATCH 8192
#define N_EDGES 1000000
#define NNZ (2 * N_EDGES)
#define NNZ_PAD_MAX (NNZ + 8 * N_NODES)
#define N_LAYERS 3
#define ALPHA 0.1f
#define GAMMA 0.01f
#define NGRP 8                    /* one group per XCD (blockIdx % 8 heuristic) */
#define FP8_SCALE 32.0f           /* keep fp8 values in e4m3 normal range */
#define INV_FP8_SCALE (1.0f / FP8_SCALE)

#define SCAN_BLOCKS 256
#define SCAN_CHUNK ((N_NODES + SCAN_BLOCKS - 1) / SCAN_BLOCKS)   /* 547 */
#define SCAN_PER_THREAD ((SCAN_CHUNK + 255) / 256)               /* 3 */

typedef float f32x2 __attribute__((ext_vector_type(2)));

// ---------- bf16 pack/unpack (RNE) -------------------------------------------
__device__ inline unsigned int f2bf(float x) {
    const unsigned int b = __float_as_uint(x);
    return (b + 0x7FFFu + ((b >> 16) & 1u)) >> 16;
}
__device__ inline float bfl(unsigned int w) { return __uint_as_float(w << 16); }
__device__ inline float bfh(unsigned int w) { return __uint_as_float(w & 0xFFFF0000u); }

__device__ inline int node_grp(int row) {        // static range group, ~nnz-balanced
    return (int)(((long long)row * NGRP) / N_NODES);
}

// ---------------- CSR build step 1: degree histogram (XCD-grouped, nt loads) --
__global__ void hist_kernel(const int* __restrict__ edge_user,
                            const int* __restrict__ edge_item,
                            int* __restrict__ deg) {
    const int g = blockIdx.x & (NGRP - 1);
    int i = (blockIdx.x >> 3) * blockDim.x + threadIdx.x;
    const int stride = (gridDim.x >> 3) * blockDim.x;
    for (; i < N_EDGES; i += stride) {
        const int u = __builtin_nontemporal_load(&edge_user[i]);
        const int v = __builtin_nontemporal_load(&edge_item[i]);
        if (node_grp(u) == g) atomicAdd(&deg[u], 1);
        const int r2 = N_USERS + v;
        if (node_grp(r2) == g) atomicAdd(&deg[r2], 1);
    }
}

// ---------------- CSR scan phase 1: per-block sums of PADDED degrees ----------
__global__ void partial_kernel(const int* __restrict__ deg, int* __restrict__ bsum) {
    const int b = blockIdx.x;
    const int t = threadIdx.x;
    const int base = b * SCAN_CHUNK + t * SCAN_PER_THREAD;
    const int lim = min((b + 1) * SCAN_CHUNK, N_NODES);
    int s = 0;
    #pragma unroll
    for (int k = 0; k < SCAN_PER_THREAD; ++k) {
        const int i = base + k;
        if (i < lim) s += (deg[i] + 7) & ~7;
    }
    __shared__ int red[4];
    #pragma unroll
    for (int off = 32; off > 0; off >>= 1) s += __shfl_down(s, off);
    const int lane = t & 63, wid = t >> 6;
    if (lane == 0) red[wid] = s;
    __syncthreads();
    if (t == 0) bsum[b] = red[0] + red[1] + red[2] + red[3];
}

// ---------------- CSR scan phase 2: scan 256 block sums -----------------------
__global__ void scanb_kernel(const int* __restrict__ bsum, int* __restrict__ boff,
                             int* __restrict__ row_start) {
    const int t = threadIdx.x;        // 256 threads
    const int lane = t & 63, wid = t >> 6;
    const int v = bsum[t];
    int x = v;
    #pragma unroll
    for (int off = 1; off < 64; off <<= 1) {
        const int y = __shfl_up(x, off);
        if (lane >= off) x += y;
    }
    __shared__ int wtot[4];
    if (lane == 63) wtot[wid] = x;
    __syncthreads();
    int wo = 0;
    for (int k = 0; k < wid; ++k) wo += wtot[k];
    boff[t] = wo + x - v;
    if (t == 255) row_start[N_NODES] = wo + x;   // padded nnz total
}

// -- CSR scan phase 3: emit row_start/row_cur/inv_sqrt + pad fill --------------
__global__ void emit_kernel(const int* __restrict__ deg, const int* __restrict__ boff,
                            int* __restrict__ row_start, int* __restrict__ row_cur,
                            float* __restrict__ inv_sqrt,
                            int* __restrict__ csr_col) {
    const int b = blockIdx.x;
    const int t = threadIdx.x;
    const int lane = t & 63, wid = t >> 6;
    const int base = b * SCAN_CHUNK + t * SCAN_PER_THREAD;
    const int lim = min((b + 1) * SCAN_CHUNK, N_NODES);
    int d[SCAN_PER_THREAD], dp[SCAN_PER_THREAD];
    int s = 0;
    #pragma unroll
    for (int k = 0; k < SCAN_PER_THREAD; ++k) {
        const int i = base + k;
        d[k]  = (i < lim) ? deg[i] : 0;
        dp[k] = (d[k] + 7) & ~7;
        s += dp[k];
    }
    int x = s;
    #pragma unroll
    for (int off = 1; off < 64; off <<= 1) {
        const int y = __shfl_up(x, off);
        if (lane >= off) x += y;
    }
    __shared__ int wtot[4];
    if (lane == 63) wtot[wid] = x;
    __syncthreads();
    int wo = boff[b];
    for (int k = 0; k < wid; ++k) wo += wtot[k];
    int p = wo + x - s;
    #pragma unroll
    for (int k = 0; k < SCAN_PER_THREAD; ++k) {
        const int i = base + k;
        if (i < lim) {
            row_start[i] = p;
            row_cur[i]   = p;
            inv_sqrt[i]  = (d[k] > 0) ? (1.0f / sqrtf((float)d[k])) : 0.0f;
            for (int q = d[k]; q < dp[k]; ++q) csr_col[p + q] = N_NODES; // dummy
            p += dp[k];
        }
    }
}

// ---------------- CSR build: scatter edge cols (XCD-grouped, nt loads) --------
__global__ void scatter_kernel(const int* __restrict__ edge_user,
                               const int* __restrict__ edge_item,
                               int* __restrict__ row_cur,
                               int* __restrict__ csr_col) {
    const int g = blockIdx.x & (NGRP - 1);
    int i = (blockIdx.x >> 3) * blockDim.x + threadIdx.x;
    const int stride = (gridDim.x >> 3) * blockDim.x;
    for (; i < N_EDGES; i += stride) {
        const int u = __builtin_nontemporal_load(&edge_user[i]);
        const int v = __builtin_nontemporal_load(&edge_item[i]);
        if (node_grp(u) == g) {
            const int pos = atomicAdd(&row_cur[u], 1);
            csr_col[pos] = N_USERS + v;
        }
        const int r2 = N_USERS + v;
        if (node_grp(r2) == g) {
            const int pos = atomicAdd(&row_cur[r2], 1);
            csr_col[pos] = u;
        }
    }
}

// ---------------- zero the dummy row (N_NODES) of all 4 fp8 buffers -----------
__global__ void zero_rows_kernel(unsigned int* __restrict__ e0,
                                 unsigned int* __restrict__ e1,
                                 unsigned int* __restrict__ e2,
                                 unsigned int* __restrict__ e3) {
    const int t = threadIdx.x;   // 128 threads
    unsigned int* bufs[4] = {e0, e1, e2, e3};
    bufs[t >> 5][(size_t)N_NODES * EMBQ + (t & 31)] = 0u;
}

// -------- init: e0 = fp8(S * inv_sqrt * x0); x0b = bf16(x0) -------------------
__global__ void init_kernel(const float* __restrict__ user_emb,
                            const float* __restrict__ item_emb,
                            const float* __restrict__ inv_sqrt,
                            unsigned int* __restrict__ e0,
                            unsigned int* __restrict__ x0b) {
    const int total = N_NODES * EMBQ;
    int i = blockIdx.x * blockDim.x + threadIdx.x;
    const int stride = gridDim.x * blockDim.x;
    for (; i < total; i += stride) {
        const int node = i >> 5;           // /EMBQ
        const int q    = i & 31;
        float4 v;
        if (node < N_USERS)
            v = ((const float4*)(user_emb + (size_t)node * EMB))[q];
        else
            v = ((const float4*)(item_emb + (size_t)(node - N_USERS) * EMB))[q];
        const float n = FP8_SCALE * inv_sqrt[node];
        int pk = __builtin_amdgcn_cvt_pk_fp8_f32(n * v.x, n * v.y, 0, false);
        pk = __builtin_amdgcn_cvt_pk_fp8_f32(n * v.z, n * v.w, pk, true);
        e0[i] = (unsigned int)pk;
        const size_t xb = (size_t)node * EMBH + q * 2;
        x0b[xb]     = f2bf(v.x) | (f2bf(v.y) << 16);
        x0b[xb + 1] = f2bf(v.z) | (f2bf(v.w) << 16);
    }
}

// ---------------- SpMM (fp8, padded CSR): w'[r] = n[r]^2 * sum w[c] -----------
// wave per row; halves take alternate edges; unroll 4 => 4 col loads + 4
// gathers independent and in flight (breaks the col->gather latency chain).
__global__ void spmm_fp8_kernel(const unsigned int* __restrict__ cur,
                                unsigned int* __restrict__ nxt,
                                const int* __restrict__ row_start,
                                const int* __restrict__ csr_col,
                                const float* __restrict__ inv_sqrt) {
    const int lane = threadIdx.x & 63;
    const int half = lane >> 5;
    const int sub  = lane & 31;
    const int w = blockIdx.x * (blockDim.x >> 6) + (threadIdx.x >> 6);
    if (w >= N_NODES) return;
    const int beg = row_start[w];
    const int end = row_start[w + 1];       // padded: (end-beg) % 8 == 0
    float s0 = 0.f, s1 = 0.f, s2 = 0.f, s3 = 0.f;
    for (int j = beg + half; j < end; j += 8) {
        const int c0 = csr_col[j];
        const int c1 = csr_col[j + 2];
        const int c2 = csr_col[j + 4];
        const int c3 = csr_col[j + 6];
        const unsigned int v0 = cur[(size_t)c0 * EMBQ + sub];
        const unsigned int v1 = cur[(size_t)c1 * EMBQ + sub];
        const unsigned int v2 = cur[(size_t)c2 * EMBQ + sub];
        const unsigned int v3 = cur[(size_t)c3 * EMBQ + sub];
        const f32x2 l0 = __builtin_amdgcn_cvt_pk_f32_fp8((int)v0, false);
        const f32x2 h0 = __builtin_amdgcn_cvt_pk_f32_fp8((int)v0, true);
        const f32x2 l1 = __builtin_amdgcn_cvt_pk_f32_fp8((int)v1, false);
        const f32x2 h1 = __builtin_amdgcn_cvt_pk_f32_fp8((int)v1, true);
        const f32x2 l2 = __builtin_amdgcn_cvt_pk_f32_fp8((int)v2, false);
        const f32x2 h2 = __builtin_amdgcn_cvt_pk_f32_fp8((int)v2, true);
        const f32x2 l3 = __builtin_amdgcn_cvt_pk_f32_fp8((int)v3, false);
        const f32x2 h3 = __builtin_amdgcn_cvt_pk_f32_fp8((int)v3, true);
        s0 += (l0.x + l1.x) + (l2.x + l3.x);
        s1 += (l0.y + l1.y) + (l2.y + l3.y);
        s2 += (h0.x + h1.x) + (h2.x + h3.x);
        s3 += (h0.y + h1.y) + (h2.y + h3.y);
    }
    s0 += __shfl_down(s0, 32);
    s1 += __shfl_down(s1, 32);
    s2 += __shfl_down(s2, 32);
    s3 += __shfl_down(s3, 32);
    if (half == 0) {
        const float n = inv_sqrt[w];
        const float sc = n * n;
        int pk = __builtin_amdgcn_cvt_pk_fp8_f32(sc * s0, sc * s1, 0, false);
        pk = __builtin_amdgcn_cvt_pk_fp8_f32(sc * s2, sc * s3, pk, true);
        nxt[(size_t)w * EMBQ + sub] = (unsigned int)pk;
    }
}

__device__ inline float logsigmoidf(float x) {
    return (x >= 0.f) ? -log1pf(expf(-x)) : (x - log1pf(expf(x)));
}

// ---------------- fused losses ------------------------------------------------
// acc-row on the fly: x0(bf16) + sqrt(deg)/S * (w1+w2+w3 fp8), dot, /16.
__global__ void loss_kernel(const unsigned int* __restrict__ x0b,
                            const unsigned short* __restrict__ e1,
                            const unsigned short* __restrict__ e2,
                            const unsigned short* __restrict__ e3,
                            const int* __restrict__ deg,
                            const int* __restrict__ users,
                            const int* __restrict__ pos_items,
                            const int* __restrict__ neg_items,
                            const int* __restrict__ sampled_user,
                            const int* __restrict__ sampled_items,
                            float* __restrict__ sums) {
    const int lane = threadIdx.x & 63;     // dims 2*lane, 2*lane+1
    const int wid  = threadIdx.x >> 6;     // 0..3
    const int gw   = blockIdx.x * 4 + wid;
    const int nw   = gridDim.x * 4;
    float s_bce = 0.f, s_pred = 0.f, s_plogp = 0.f, s_ul = 0.f;
    for (int p = gw; p < 4 * BATCH; p += nw) {
        int u, it;
        if (p < 2 * BATCH) {
            if (p < BATCH) { u = users[p];          it = pos_items[p]; }
            else           { u = users[p - BATCH];  it = neg_items[p - BATCH]; }
        } else {
            const int q = p - 2 * BATCH;
            u = sampled_user[q]; it = sampled_items[q];
        }
        const float sdu = sqrtf((float)deg[u]) * INV_FP8_SCALE;
        const unsigned int a0 = x0b[(size_t)u * EMBH + lane];
        const size_t ui = (size_t)u * 64 + lane;
        const f32x2 u1 = __builtin_amdgcn_cvt_pk_f32_fp8((int)e1[ui], false);
        const f32x2 u2 = __builtin_amdgcn_cvt_pk_f32_fp8((int)e2[ui], false);
        const f32x2 u3 = __builtin_amdgcn_cvt_pk_f32_fp8((int)e3[ui], false);
        const float ax = bfl(a0) + sdu * (u1.x + u2.x + u3.x);
        const float ay = bfh(a0) + sdu * (u1.y + u2.y + u3.y);
        const int itn = N_USERS + it;
        const float sdi = sqrtf((float)deg[itn]) * INV_FP8_SCALE;
        const unsigned int b0 = x0b[(size_t)itn * EMBH + lane];
        const size_t ii = (size_t)itn * 64 + lane;
        const f32x2 i1 = __builtin_amdgcn_cvt_pk_f32_fp8((int)e1[ii], false);
        const f32x2 i2 = __builtin_amdgcn_cvt_pk_f32_fp8((int)e2[ii], false);
        const f32x2 i3 = __builtin_amdgcn_cvt_pk_f32_fp8((int)e3[ii], false);
        const float bx = bfl(b0) + sdi * (i1.x + i2.x + i3.x);
        const float by = bfh(b0) + sdi * (i1.y + i2.y + i3.y);
        float d = ax * bx + ay * by;
        #pragma unroll
        for (int off = 32; off > 0; off >>= 1) d += __shfl_down(d, off);
        if (lane == 0) {
            d *= (1.f / 16.f);                  // (acc/4)·(acc/4)
            const float pred = 1.f / (1.f + expf(-d));
            if (p < 2 * BATCH) {
                const float ls  = logsigmoidf(d);
                const float lsn = logsigmoidf(-d);
                s_bce   += (p < BATCH) ? -ls : -lsn;
                s_pred  += pred;
                s_plogp += pred * ls;
            } else {
                s_ul += pred;
            }
        }
    }
    __shared__ float red[4][4];
    if (lane == 0) {
        red[wid][0] = s_bce; red[wid][1] = s_pred;
        red[wid][2] = s_plogp; red[wid][3] = s_ul;
    }
    __syncthreads();
    if (threadIdx.x < 4) {
        const float v = red[0][threadIdx.x] + red[1][threadIdx.x]
                      + red[2][threadIdx.x] + red[3][threadIdx.x];
        atomicAdd(&sums[threadIdx.x], v);
    }
}

// ---------------- finalize ----------------------------------------------------
__global__ void finalize_kernel(const float* __restrict__ sums, float* __restrict__ out) {
    if (threadIdx.x == 0 && blockIdx.x == 0) {
        const float n = 2.f * BATCH;
        const float bce        = sums[0] / n;
        const float pred_avg   = sums[1] / n;
        const float plogp_avg  = sums[2] / n;
        const float predul_avg = sums[3] / n;
        const float info = ALPHA * (-pred_avg * logf(predul_avg)
                                    - (1.f - pred_avg) * logf(1.f - predul_avg))
                         + GAMMA * plogp_avg;
        out[0] = bce;
        out[1] = info;
    }
}

extern "C" void kernel_launch(void* const* d_in, const int* in_sizes, int n_in,
                              void* d_out, int out_size, void* d_ws, size_t ws_size,
                              hipStream_t stream) {
    const float* user_emb      = (const float*)d_in[0];
    const float* item_emb      = (const float*)d_in[1];
    const int*   edge_user     = (const int*)d_in[3];
    const int*   edge_item     = (const int*)d_in[4];
    const int*   users         = (const int*)d_in[5];
    const int*   pos_items     = (const int*)d_in[6];
    const int*   neg_items     = (const int*)d_in[7];
    const int*   sampled_user  = (const int*)d_in[8];
    const int*   sampled_items = (const int*)d_in[9];
    float* out = (float*)d_out;

    const size_t ebytes = (size_t)(N_NODES + 1) * EMBQ * sizeof(unsigned int); // 17.9 MB
    char* ws = (char*)d_ws;
    size_t off = 0;
    unsigned int* e0  = (unsigned int*)(ws + off); off += ebytes;
    unsigned int* e1  = (unsigned int*)(ws + off); off += ebytes;
    unsigned int* e2  = (unsigned int*)(ws + off); off += ebytes;
    unsigned int* e3  = (unsigned int*)(ws + off); off += ebytes;
    unsigned int* x0b = (unsigned int*)(ws + off); off += (size_t)N_NODES * EMBH * 4;
    float* sums = (float*)(ws + off); off += 256;
    int*   deg       = (int*)(ws + off); off += (size_t)N_NODES * 4;
    int*   row_start = (int*)(ws + off); off += (size_t)(N_NODES + 1) * 4 + 252;
    int*   row_cur   = (int*)(ws + off); off += (size_t)N_NODES * 4;
    float* inv_sqrt  = (float*)(ws + off); off += (size_t)N_NODES * 4;
    int*   csr_col   = (int*)(ws + off); off += (size_t)NNZ_PAD_MAX * 4;
    int*   bsum      = (int*)(ws + off); off += (size_t)SCAN_BLOCKS * 4;
    int*   boff      = (int*)(ws + off); off += (size_t)SCAN_BLOCKS * 4;

    hipMemsetAsync(deg, 0, (size_t)N_NODES * 4, stream);
    hipMemsetAsync(sums, 0, 4 * sizeof(float), stream);

    hist_kernel<<<2048, 256, 0, stream>>>(edge_user, edge_item, deg);
    partial_kernel<<<SCAN_BLOCKS, 256, 0, stream>>>(deg, bsum);
    scanb_kernel<<<1, 256, 0, stream>>>(bsum, boff, row_start);
    emit_kernel<<<SCAN_BLOCKS, 256, 0, stream>>>(deg, boff, row_start, row_cur,
                                                 inv_sqrt, csr_col);
    scatter_kernel<<<2048, 256, 0, stream>>>(edge_user, edge_item, row_cur, csr_col);
    zero_rows_kernel<<<1, 128, 0, stream>>>(e0, e1, e2, e3);
    init_kernel<<<4096, 256, 0, stream>>>(user_emb, item_emb, inv_sqrt, e0, x0b);

    spmm_fp8_kernel<<<(N_NODES + 3) / 4, 256, 0, stream>>>(e0, e1, row_start,
                                                           csr_col, inv_sqrt);
    spmm_fp8_kernel<<<(N_NODES + 3) / 4, 256, 0, stream>>>(e1, e2, row_start,
                                                           csr_col, inv_sqrt);
    spmm_fp8_kernel<<<(N_NODES + 3) / 4, 256, 0, stream>>>(e2, e3, row_start,
                                                           csr_col, inv_sqrt);

    loss_kernel<<<512, 256, 0, stream>>>(x0b,
                                         (const unsigned short*)e1,
                                         (const unsigned short*)e2,
                                         (const unsigned short*)e3,
                                         deg, users, pos_items, neg_items,
                                         sampled_user, sampled_items, sums);
    finalize_kernel<<<1, 1, 0, stream>>>(sums, out);
}